// Round 1
// baseline (1257.924 us; speedup 1.0000x reference)
//
#include <hip/hip_runtime.h>
#include <hip/hip_bf16.h>

#define DEV __device__ __forceinline__

typedef __attribute__((ext_vector_type(4))) float f32x4;
typedef __attribute__((ext_vector_type(8))) __bf16 bf16v;
typedef __attribute__((ext_vector_type(8))) unsigned short u16x8;
typedef __attribute__((ext_vector_type(4))) unsigned short u16x4;

DEV unsigned short f2b(float x) {
    unsigned u = __builtin_bit_cast(unsigned, x);
    unsigned r = u + 0x7FFF + ((u >> 16) & 1);
    return (unsigned short)(r >> 16);
}

DEV void gl_lds16(const void* g, void* l) {
    __builtin_amdgcn_global_load_lds(
        (const __attribute__((address_space(1))) unsigned*)g,
        (__attribute__((address_space(3))) unsigned*)l,
        16, 0, 0);
}

// ---------------- small kernels ----------------

__global__ __launch_bounds__(256) void cvt_f32_bf16(const float* __restrict__ in,
                                                    unsigned short* __restrict__ out, long n) {
    long i = ((long)blockIdx.x * 256 + threadIdx.x) * 4;
    if (i >= n) return;
    float4 f = *(const float4*)(in + i);
    u16x4 u;
    u[0] = f2b(f.x); u[1] = f2b(f.y); u[2] = f2b(f.z); u[3] = f2b(f.w);
    *(u16x4*)(out + i) = u;
}

__global__ __launch_bounds__(256) void transp_f32_bf16(const float* __restrict__ in,
                                                       unsigned short* __restrict__ out,
                                                       int R, int C) {
    __shared__ float t[32][33];
    int tx = threadIdx.x & 31, ty = threadIdx.x >> 5;
    long c0 = (long)blockIdx.x * 32, r0 = (long)blockIdx.y * 32;
#pragma unroll
    for (int i = 0; i < 4; i++)
        t[ty + i * 8][tx] = in[(r0 + ty + i * 8) * C + c0 + tx];
    __syncthreads();
#pragma unroll
    for (int i = 0; i < 4; i++)
        out[(c0 + ty + i * 8) * R + r0 + tx] = f2b(t[tx][ty + i * 8]);
}

__global__ __launch_bounds__(256) void transp_bf16(const unsigned short* __restrict__ in,
                                                   unsigned short* __restrict__ out,
                                                   int R, int C, long zin, long zout) {
    in += (long)blockIdx.z * zin;
    out += (long)blockIdx.z * zout;
    __shared__ unsigned short t[32][33];
    int tx = threadIdx.x & 31, ty = threadIdx.x >> 5;
    long c0 = (long)blockIdx.x * 32, r0 = (long)blockIdx.y * 32;
#pragma unroll
    for (int i = 0; i < 4; i++)
        t[ty + i * 8][tx] = in[(r0 + ty + i * 8) * C + c0 + tx];
    __syncthreads();
#pragma unroll
    for (int i = 0; i < 4; i++)
        out[(c0 + ty + i * 8) * R + r0 + tx] = t[tx][ty + i * 8];
}

DEV float waveMax(float v) {
#pragma unroll
    for (int o = 32; o > 0; o >>= 1) v = fmaxf(v, __shfl_xor(v, o));
    return v;
}
DEV float waveSum(float v) {
#pragma unroll
    for (int o = 32; o > 0; o >>= 1) v += __shfl_xor(v, o);
    return v;
}

__global__ __launch_bounds__(256) void softmax_rows(float* __restrict__ a) {
    float* p = a + (long)blockIdx.x * 2048;
    __shared__ float red[4];
    int t = threadIdx.x, lane = t & 63, wave = t >> 6;
    float4 v0 = ((float4*)p)[t];
    float4 v1 = ((float4*)p)[t + 256];
    float m = fmaxf(fmaxf(fmaxf(v0.x, v0.y), fmaxf(v0.z, v0.w)),
                    fmaxf(fmaxf(v1.x, v1.y), fmaxf(v1.z, v1.w)));
    m = waveMax(m);
    if (lane == 0) red[wave] = m;
    __syncthreads();
    m = fmaxf(fmaxf(red[0], red[1]), fmaxf(red[2], red[3]));
    __syncthreads();
    v0.x = __expf(v0.x - m); v0.y = __expf(v0.y - m);
    v0.z = __expf(v0.z - m); v0.w = __expf(v0.w - m);
    v1.x = __expf(v1.x - m); v1.y = __expf(v1.y - m);
    v1.z = __expf(v1.z - m); v1.w = __expf(v1.w - m);
    float s = v0.x + v0.y + v0.z + v0.w + v1.x + v1.y + v1.z + v1.w;
    s = waveSum(s);
    if (lane == 0) red[wave] = s;
    __syncthreads();
    s = red[0] + red[1] + red[2] + red[3];
    float inv = 1.0f / s;
    v0.x *= inv; v0.y *= inv; v0.z *= inv; v0.w *= inv;
    v1.x *= inv; v1.y *= inv; v1.z *= inv; v1.w *= inv;
    ((float4*)p)[t] = v0;
    ((float4*)p)[t + 256] = v1;
}

__global__ __launch_bounds__(256) void ln_rows(const float* __restrict__ in,
                                               const float* __restrict__ g,
                                               const float* __restrict__ b,
                                               float* __restrict__ outF,
                                               unsigned short* __restrict__ outB) {
    const float* p = in + (long)blockIdx.x * 1024;
    __shared__ float red[4], red2[4];
    int t = threadIdx.x, lane = t & 63, wave = t >> 6;
    float4 v = ((const float4*)p)[t];
    float s = v.x + v.y + v.z + v.w;
    float q = v.x * v.x + v.y * v.y + v.z * v.z + v.w * v.w;
    s = waveSum(s); q = waveSum(q);
    if (lane == 0) { red[wave] = s; red2[wave] = q; }
    __syncthreads();
    s = red[0] + red[1] + red[2] + red[3];
    q = red2[0] + red2[1] + red2[2] + red2[3];
    float mean = s * (1.0f / 1024.0f);
    float var = q * (1.0f / 1024.0f) - mean * mean;
    float rstd = rsqrtf(var + 1e-10f);
    float4 gg = ((const float4*)g)[t];
    float4 bb = ((const float4*)b)[t];
    float4 o;
    o.x = gg.x * ((v.x - mean) * rstd) + bb.x;
    o.y = gg.y * ((v.y - mean) * rstd) + bb.y;
    o.z = gg.z * ((v.z - mean) * rstd) + bb.z;
    o.w = gg.w * ((v.w - mean) * rstd) + bb.w;
    ((float4*)(outF + (long)blockIdx.x * 1024))[t] = o;
    if (outB) {
        u16x4 u;
        u[0] = f2b(o.x); u[1] = f2b(o.y); u[2] = f2b(o.z); u[3] = f2b(o.w);
        *(u16x4*)(outB + (long)blockIdx.x * 1024 + (long)t * 4) = u;
    }
}

// ---------------- generic MFMA GEMM ----------------

enum { M_QKV = 0, M_SCORES = 1, M_PV = 2, M_RES = 3, M_RELU = 4 };

struct GArgs {
    const unsigned short* A;
    const float* Af;
    long lda;
    const unsigned short* B;
    long ldb;
    const float* bias;
    const float* resid;
    float* outF;
    unsigned short* outB;
    long ldo;
    int K;
    float scale;
};

template <int BM, int BN, int WR, int WC, int MODE>
__global__ __launch_bounds__(256) void gemm_k(GArgs g) {
    constexpr int MI = BM / (WR * 16), NI = BN / (WC * 16);
    __shared__ __align__(16) char sm[(BM + BN) * 128];
    char* sA = sm;
    char* sB = sm + BM * 128;
    const int tid = threadIdx.x, lane = tid & 63, wave = tid >> 6;
    const int wr = wave / WC, wc = wave % WC;
    const long m0 = (long)blockIdx.x * BM, n0 = (long)blockIdx.y * BN;
    const int z = blockIdx.z;

    const char* Ab = nullptr;
    const float* Af = nullptr;
    const char* Bb;
    const long lda = g.lda, ldb = g.ldb;
    if constexpr (MODE == M_SCORES) {
        Ab = (const char*)(g.A + (long)z * 131072 + m0 * lda);
        Bb = (const char*)(g.B + (long)z * 131072 + n0 * ldb);
    } else if constexpr (MODE == M_PV) {
        Af = g.Af + (long)z * 4194304 + m0 * lda;
        Bb = (const char*)(g.B + (long)z * 131072 + n0 * ldb);
    } else {
        Ab = (const char*)(g.A + m0 * lda);
        Bb = (const char*)(g.B + n0 * ldb);
    }

    f32x4 acc[MI][NI];
#pragma unroll
    for (int mi = 0; mi < MI; mi++)
#pragma unroll
        for (int ni = 0; ni < NI; ni++) acc[mi][ni] = (f32x4)(0.0f);

    for (int k0 = 0; k0 < g.K; k0 += 64) {
        if constexpr (MODE == M_PV) {
            // reg-stage attn fp32 -> bf16 LDS tile, source-swizzled
#pragma unroll
            for (int i = 0; i < (BM * 128) / 4096; i++) {
                int p = (i * 256 + tid) * 16;
                int row = p >> 7, cb = p & 127;
                int scb = cb ^ ((row & 7) << 4);
                const float* s = Af + (long)row * lda + k0 + (scb >> 1);
                float4 f0 = *(const float4*)s;
                float4 f1 = *(const float4*)(s + 4);
                u16x8 u;
                u[0] = f2b(f0.x); u[1] = f2b(f0.y); u[2] = f2b(f0.z); u[3] = f2b(f0.w);
                u[4] = f2b(f1.x); u[5] = f2b(f1.y); u[6] = f2b(f1.z); u[7] = f2b(f1.w);
                *(u16x8*)(sA + p) = u;
            }
        } else {
#pragma unroll
            for (int i = 0; i < BM / 32; i++) {
                int c = i * 4 + wave;
                int p = c * 1024 + lane * 16;
                int row = p >> 7;
                int scb = (p & 127) ^ ((row & 7) << 4);
                gl_lds16(Ab + (long)row * (lda * 2) + (long)k0 * 2 + scb, sA + c * 1024);
            }
        }
#pragma unroll
        for (int i = 0; i < BN / 32; i++) {
            int c = i * 4 + wave;
            int p = c * 1024 + lane * 16;
            int row = p >> 7;
            int scb = (p & 127) ^ ((row & 7) << 4);
            gl_lds16(Bb + (long)row * (ldb * 2) + (long)k0 * 2 + scb, sB + c * 1024);
        }
        __syncthreads();
#pragma unroll
        for (int ks = 0; ks < 2; ++ks) {
            const int cb = ks * 64 + (lane >> 4) * 16;
            bf16v af[MI], bfv[NI];
#pragma unroll
            for (int mi = 0; mi < MI; mi++) {
                int r = wr * (BM / WR) + mi * 16 + (lane & 15);
                af[mi] = *(const bf16v*)(sA + r * 128 + (cb ^ ((r & 7) << 4)));
            }
#pragma unroll
            for (int ni = 0; ni < NI; ni++) {
                int r = wc * (BN / WC) + ni * 16 + (lane & 15);
                bfv[ni] = *(const bf16v*)(sB + r * 128 + (cb ^ ((r & 7) << 4)));
            }
#pragma unroll
            for (int mi = 0; mi < MI; mi++)
#pragma unroll
                for (int ni = 0; ni < NI; ni++)
                    acc[mi][ni] = __builtin_amdgcn_mfma_f32_16x16x32_bf16(
                        af[mi], bfv[ni], acc[mi][ni], 0, 0, 0);
        }
        __syncthreads();
    }

    // epilogue: C/D layout col=lane&15, row=(lane>>4)*4+j (HW-verified)
#pragma unroll
    for (int mi = 0; mi < MI; mi++)
#pragma unroll
        for (int ni = 0; ni < NI; ni++)
#pragma unroll
            for (int j = 0; j < 4; j++) {
                long r = m0 + wr * (BM / WR) + mi * 16 + (lane >> 4) * 4 + j;
                long c = n0 + wc * (BN / WC) + ni * 16 + (lane & 15);
                float v = acc[mi][ni][j];
                if constexpr (MODE == M_QKV) {
                    v += g.bias[c];
                    long b = r >> 11, s = r & 2047, h = c >> 6, d = c & 63;
                    g.outB[((b * 16 + h) * 2048 + s) * 64 + d] = f2b(v);
                } else if constexpr (MODE == M_SCORES) {
                    g.outF[(long)z * 4194304 + r * 2048 + c] = v * g.scale;
                } else if constexpr (MODE == M_PV) {
                    long tok = (long)(z >> 4) * 2048 + r;
                    g.outB[tok * 1024 + (long)(z & 15) * 64 + c] = f2b(v);
                } else if constexpr (MODE == M_RES) {
                    long i = r * g.ldo + c;
                    g.outF[i] = v + g.bias[c] + g.resid[i];
                } else {  // M_RELU
                    float t = v + g.bias[c];
                    g.outB[r * g.ldo + c] = f2b(t > 0.0f ? t : 0.0f);
                }
            }
}

// ---------------- host ----------------

extern "C" void kernel_launch(void* const* d_in, const int* in_sizes, int n_in,
                              void* d_out, int out_size, void* d_ws, size_t ws_size,
                              hipStream_t stream) {
    const float* x = (const float*)d_in[0];
    const float* wq = (const float*)d_in[1];
    const float* bq = (const float*)d_in[2];
    const float* wk = (const float*)d_in[3];
    const float* bk = (const float*)d_in[4];
    const float* wv = (const float*)d_in[5];
    const float* bv = (const float*)d_in[6];
    const float* wo = (const float*)d_in[7];
    const float* bo = (const float*)d_in[8];
    const float* g1 = (const float*)d_in[9];
    const float* b1 = (const float*)d_in[10];
    const float* w1 = (const float*)d_in[11];
    const float* bf1 = (const float*)d_in[12];
    const float* w2 = (const float*)d_in[13];
    const float* bf2 = (const float*)d_in[14];
    const float* g2 = (const float*)d_in[15];
    const float* b2 = (const float*)d_in[16];

    float* out2 = (float*)d_out;
    float* attn = (float*)d_out + 8388608;

    char* ws = (char*)d_ws;
    size_t off = 0;
    auto alc = [&](size_t bytes) { size_t r = off; off += (bytes + 255) & ~(size_t)255; return r; };

    unsigned short* xb  = (unsigned short*)(ws + alc(16777216));
    unsigned short* wqT = (unsigned short*)(ws + alc(2097152));
    unsigned short* wkT = (unsigned short*)(ws + alc(2097152));
    unsigned short* wvT = (unsigned short*)(ws + alc(2097152));
    unsigned short* woT = (unsigned short*)(ws + alc(2097152));
    unsigned short* w1T = (unsigned short*)(ws + alc(8388608));
    unsigned short* w2T = (unsigned short*)(ws + alc(8388608));
    size_t qkvOff = alc(67108864);           // q,k,v,vt block; later reused by ff1
    unsigned short* qb = (unsigned short*)(ws + qkvOff);
    unsigned short* kb = qb + 8388608;
    unsigned short* vb = kb + 8388608;
    unsigned short* vt = vb + 8388608;
    unsigned short* ff1 = qb;                // alias (q/k/v/vt dead by FFN1)
    size_t aoOff = alc(16777216);            // attn_out bf16; later out1 bf16
    unsigned short* ao  = (unsigned short*)(ws + aoOff);
    unsigned short* o1b = ao;                // alias (ao dead after out-proj)
    size_t rOff = alc(33554432);             // resid1; later resid2
    float* r1 = (float*)(ws + rOff);
    float* r2 = r1;                          // alias
    float* o1f = (float*)(ws + alc(33554432));

    // 1. x -> bf16
    cvt_f32_bf16<<<8192, 256, 0, stream>>>(x, xb, 8388608);
    // 2. weight transposes -> [N][K] bf16
    transp_f32_bf16<<<dim3(32, 32), 256, 0, stream>>>(wq, wqT, 1024, 1024);
    transp_f32_bf16<<<dim3(32, 32), 256, 0, stream>>>(wk, wkT, 1024, 1024);
    transp_f32_bf16<<<dim3(32, 32), 256, 0, stream>>>(wv, wvT, 1024, 1024);
    transp_f32_bf16<<<dim3(32, 32), 256, 0, stream>>>(wo, woT, 1024, 1024);
    transp_f32_bf16<<<dim3(128, 32), 256, 0, stream>>>(w1, w1T, 1024, 4096);
    transp_f32_bf16<<<dim3(32, 128), 256, 0, stream>>>(w2, w2T, 4096, 1024);

    // 3. QKV projections -> [b][h][s][d] bf16
    {
        GArgs a{};
        a.A = xb; a.lda = 1024; a.ldb = 1024; a.K = 1024;
        a.B = wqT; a.bias = bq; a.outB = qb;
        gemm_k<128, 128, 2, 2, M_QKV><<<dim3(64, 8, 1), 256, 0, stream>>>(a);
        a.B = wkT; a.bias = bk; a.outB = kb;
        gemm_k<128, 128, 2, 2, M_QKV><<<dim3(64, 8, 1), 256, 0, stream>>>(a);
        a.B = wvT; a.bias = bv; a.outB = vb;
        gemm_k<128, 128, 2, 2, M_QKV><<<dim3(64, 8, 1), 256, 0, stream>>>(a);
    }
    // 4. v -> v^T per head: [d][s]
    transp_bf16<<<dim3(2, 64, 64), 256, 0, stream>>>(vb, vt, 2048, 64, 131072, 131072);

    // 5. scores = q k^T / 8 (raw, fp32) -> d_out.attn
    {
        GArgs a{};
        a.A = qb; a.lda = 64; a.B = kb; a.ldb = 64;
        a.outF = attn; a.K = 64; a.scale = 0.125f;
        gemm_k<128, 128, 2, 2, M_SCORES><<<dim3(16, 16, 64), 256, 0, stream>>>(a);
    }
    // 6. softmax in-place
    softmax_rows<<<131072, 256, 0, stream>>>(attn);
    // 7. out = attn @ v -> attn_out bf16 [tok][h*64+d]
    {
        GArgs a{};
        a.Af = attn; a.lda = 2048; a.B = vt; a.ldb = 2048;
        a.outB = ao; a.K = 2048;
        gemm_k<128, 64, 4, 1, M_PV><<<dim3(16, 1, 64), 256, 0, stream>>>(a);
    }
    // 8. out-proj + bias + residual(x) -> r1 fp32
    {
        GArgs a{};
        a.A = ao; a.lda = 1024; a.B = woT; a.ldb = 1024;
        a.bias = bo; a.resid = x; a.outF = r1; a.ldo = 1024; a.K = 1024;
        gemm_k<128, 128, 2, 2, M_RES><<<dim3(64, 8, 1), 256, 0, stream>>>(a);
    }
    // 9. LN1 -> o1f fp32 + o1b bf16
    ln_rows<<<8192, 256, 0, stream>>>(r1, g1, b1, o1f, o1b);
    // 10. FFN1 + ReLU -> ff1 bf16
    {
        GArgs a{};
        a.A = o1b; a.lda = 1024; a.B = w1T; a.ldb = 1024;
        a.bias = bf1; a.outB = ff1; a.ldo = 4096; a.K = 1024;
        gemm_k<128, 128, 2, 2, M_RELU><<<dim3(64, 32, 1), 256, 0, stream>>>(a);
    }
    // 11. FFN2 + bias + residual(out1) -> r2 fp32
    {
        GArgs a{};
        a.A = ff1; a.lda = 4096; a.B = w2T; a.ldb = 4096;
        a.bias = bf2; a.resid = o1f; a.outF = r2; a.ldo = 1024; a.K = 4096;
        gemm_k<128, 128, 2, 2, M_RES><<<dim3(64, 8, 1), 256, 0, stream>>>(a);
    }
    // 12. LN2 -> out2 (d_out)
    ln_rows<<<8192, 256, 0, stream>>>(r2, g2, b2, out2, nullptr);

    (void)in_sizes; (void)n_in; (void)out_size; (void)ws_size;
}

// Round 2
// 910.065 us; speedup vs baseline: 1.3822x; 1.3822x over previous
//
#include <hip/hip_runtime.h>
#include <hip/hip_bf16.h>

#define DEV __device__ __forceinline__

typedef __attribute__((ext_vector_type(4))) float f32x4;
typedef __attribute__((ext_vector_type(8))) __bf16 bf16v;
typedef __attribute__((ext_vector_type(8))) unsigned short u16x8;
typedef __attribute__((ext_vector_type(4))) unsigned short u16x4;

DEV unsigned short f2b(float x) {
    unsigned u = __builtin_bit_cast(unsigned, x);
    unsigned r = u + 0x7FFF + ((u >> 16) & 1);
    return (unsigned short)(r >> 16);
}

DEV void gl_lds16(const void* g, void* l) {
    __builtin_amdgcn_global_load_lds(
        (const __attribute__((address_space(1))) unsigned*)g,
        (__attribute__((address_space(3))) unsigned*)l,
        16, 0, 0);
}

// ---------------- small kernels ----------------

__global__ __launch_bounds__(256) void cvt_f32_bf16(const float* __restrict__ in,
                                                    unsigned short* __restrict__ out, long n) {
    long i = ((long)blockIdx.x * 256 + threadIdx.x) * 4;
    if (i >= n) return;
    float4 f = *(const float4*)(in + i);
    u16x4 u;
    u[0] = f2b(f.x); u[1] = f2b(f.y); u[2] = f2b(f.z); u[3] = f2b(f.w);
    *(u16x4*)(out + i) = u;
}

__global__ __launch_bounds__(256) void transp_f32_bf16(const float* __restrict__ in,
                                                       unsigned short* __restrict__ out,
                                                       int R, int C) {
    __shared__ float t[32][33];
    int tx = threadIdx.x & 31, ty = threadIdx.x >> 5;
    long c0 = (long)blockIdx.x * 32, r0 = (long)blockIdx.y * 32;
#pragma unroll
    for (int i = 0; i < 4; i++)
        t[ty + i * 8][tx] = in[(r0 + ty + i * 8) * C + c0 + tx];
    __syncthreads();
#pragma unroll
    for (int i = 0; i < 4; i++)
        out[(c0 + ty + i * 8) * R + r0 + tx] = f2b(t[tx][ty + i * 8]);
}

DEV float waveSum(float v) {
#pragma unroll
    for (int o = 32; o > 0; o >>= 1) v += __shfl_xor(v, o);
    return v;
}

__global__ __launch_bounds__(256) void ln_rows(const float* __restrict__ in,
                                               const float* __restrict__ g,
                                               const float* __restrict__ b,
                                               float* __restrict__ outF,
                                               unsigned short* __restrict__ outB) {
    const float* p = in + (long)blockIdx.x * 1024;
    __shared__ float red[4], red2[4];
    int t = threadIdx.x, lane = t & 63, wave = t >> 6;
    float4 v = ((const float4*)p)[t];
    float s = v.x + v.y + v.z + v.w;
    float q = v.x * v.x + v.y * v.y + v.z * v.z + v.w * v.w;
    s = waveSum(s); q = waveSum(q);
    if (lane == 0) { red[wave] = s; red2[wave] = q; }
    __syncthreads();
    s = red[0] + red[1] + red[2] + red[3];
    q = red2[0] + red2[1] + red2[2] + red2[3];
    float mean = s * (1.0f / 1024.0f);
    float var = q * (1.0f / 1024.0f) - mean * mean;
    float rstd = rsqrtf(var + 1e-10f);
    float4 gg = ((const float4*)g)[t];
    float4 bb = ((const float4*)b)[t];
    float4 o;
    o.x = gg.x * ((v.x - mean) * rstd) + bb.x;
    o.y = gg.y * ((v.y - mean) * rstd) + bb.y;
    o.z = gg.z * ((v.z - mean) * rstd) + bb.z;
    o.w = gg.w * ((v.w - mean) * rstd) + bb.w;
    ((float4*)(outF + (long)blockIdx.x * 1024))[t] = o;
    if (outB) {
        u16x4 u;
        u[0] = f2b(o.x); u[1] = f2b(o.y); u[2] = f2b(o.z); u[3] = f2b(o.w);
        *(u16x4*)(outB + (long)blockIdx.x * 1024 + (long)t * 4) = u;
    }
}

// ---------------- fused attention ----------------
// grid 8192 (128 row-blocks x 64 z), block 256 (4 waves).
// Per block: 16 q-rows of one (b,h). Q in regs, K via LDS chunks,
// full-row softmax in regs, P -> d_out fp32 + LDS bf16, then PV from L2.
__global__ __launch_bounds__(256, 2) void attn_fused(
    const unsigned short* __restrict__ qb,   // [z][2048][64] bf16
    const unsigned short* __restrict__ kb,   // [z][2048][64] bf16
    const unsigned short* __restrict__ vt,   // [z][64][2048] bf16
    float* __restrict__ attn,                // [z][2048][2048] fp32
    unsigned short* __restrict__ ao) {       // [tok][1024] bf16
    __shared__ __align__(16) char smem[65536];
    __shared__ float sredM[4][16], sredS[4][16];

    // XCD-aware swizzle: 8192 % 8 == 0, each XCD gets 1024 consecutive ids
    int id = blockIdx.x;
    int swz = (id & 7) * 1024 + (id >> 3);
    const int z = swz >> 7;
    const int m0 = (swz & 127) * 16;

    const int tid = threadIdx.x, lane = tid & 63, w = tid >> 6;
    const int g = lane >> 4, l15 = lane & 15;

    const char* qz = (const char*)(qb + (long)z * 131072);
    const char* kz = (const char*)(kb + (long)z * 131072);
    const char* vz = (const char*)(vt + (long)z * 131072);

    // Q A-frags: row = l15, k = ks*32 + g*8 + i
    const char* qrow = qz + (long)(m0 + l15) * 128;
    bf16v aq0 = *(const bf16v*)(qrow + g * 16);
    bf16v aq1 = *(const bf16v*)(qrow + 64 + g * 16);

    f32x4 acc[8][4];
#pragma unroll
    for (int c = 0; c < 8; c++)
#pragma unroll
        for (int t = 0; t < 4; t++) acc[c][t] = (f32x4)(0.0f);

    // per-lane pre-swizzled source offset (row&7 == (lane>>3)&7 within 32-row step)
    const int soff = ((lane & 7) * 16) ^ (((lane >> 3) & 7) << 4);

    for (int c = 0; c < 8; ++c) {
        const char* src = kz + (long)(c * 256 + w * 8 + (lane >> 3)) * 128 + soff;
#pragma unroll
        for (int i = 0; i < 8; ++i)
            gl_lds16(src + (long)i * 4096, smem + i * 4096 + w * 1024);
        __syncthreads();
#pragma unroll
        for (int t = 0; t < 4; ++t) {
            const int row = w * 64 + t * 16 + l15;  // within chunk; row&7 == lane&7
            const char* bp = smem + row * 128;
            const int sw = (lane & 7) << 4;
            bf16v bk0 = *(const bf16v*)(bp + ((g * 16) ^ sw));
            bf16v bk1 = *(const bf16v*)(bp + ((64 + g * 16) ^ sw));
            acc[c][t] = __builtin_amdgcn_mfma_f32_16x16x32_bf16(aq0, bk0, acc[c][t], 0, 0, 0);
            acc[c][t] = __builtin_amdgcn_mfma_f32_16x16x32_bf16(aq1, bk1, acc[c][t], 0, 0, 0);
        }
        __syncthreads();
    }

    // ---- softmax over full rows (16 rows, 2048 cols spread over 4 waves) ----
    float M[4], S[4];
#pragma unroll
    for (int j = 0; j < 4; ++j) {
        float m = -1e30f;
#pragma unroll
        for (int c = 0; c < 8; c++)
#pragma unroll
            for (int t = 0; t < 4; t++) m = fmaxf(m, acc[c][t][j]);
        m = fmaxf(m, __shfl_xor(m, 1));
        m = fmaxf(m, __shfl_xor(m, 2));
        m = fmaxf(m, __shfl_xor(m, 4));
        m = fmaxf(m, __shfl_xor(m, 8));
        M[j] = m;
    }
    if (l15 == 0) {
        sredM[w][g * 4 + 0] = M[0];
        sredM[w][g * 4 + 1] = M[1];
        sredM[w][g * 4 + 2] = M[2];
        sredM[w][g * 4 + 3] = M[3];
    }
    __syncthreads();
#pragma unroll
    for (int j = 0; j < 4; ++j) {
        int r = g * 4 + j;
        M[j] = 0.125f * fmaxf(fmaxf(sredM[0][r], sredM[1][r]),
                              fmaxf(sredM[2][r], sredM[3][r]));
        S[j] = 0.0f;
    }
#pragma unroll
    for (int c = 0; c < 8; c++)
#pragma unroll
        for (int t = 0; t < 4; t++) {
            f32x4 v = acc[c][t];
            v[0] = __expf(v[0] * 0.125f - M[0]);
            v[1] = __expf(v[1] * 0.125f - M[1]);
            v[2] = __expf(v[2] * 0.125f - M[2]);
            v[3] = __expf(v[3] * 0.125f - M[3]);
            acc[c][t] = v;
            S[0] += v[0]; S[1] += v[1]; S[2] += v[2]; S[3] += v[3];
        }
#pragma unroll
    for (int j = 0; j < 4; ++j) {
        float s = S[j];
        s += __shfl_xor(s, 1);
        s += __shfl_xor(s, 2);
        s += __shfl_xor(s, 4);
        s += __shfl_xor(s, 8);
        S[j] = s;
    }
    if (l15 == 0) {
        sredS[w][g * 4 + 0] = S[0];
        sredS[w][g * 4 + 1] = S[1];
        sredS[w][g * 4 + 2] = S[2];
        sredS[w][g * 4 + 3] = S[3];
    }
    __syncthreads();
    float inv[4];
#pragma unroll
    for (int j = 0; j < 4; ++j) {
        int r = g * 4 + j;
        inv[j] = 1.0f / (sredS[0][r] + sredS[1][r] + sredS[2][r] + sredS[3][r]);
    }

    // ---- write P: fp32 -> d_out, bf16 -> LDS (K region dead; swizzled) ----
    float* ab = attn + (long)z * 4194304 + (long)m0 * 2048;
#pragma unroll
    for (int c = 0; c < 8; c++)
#pragma unroll
        for (int t = 0; t < 4; t++) {
            const int col = c * 256 + w * 64 + t * 16 + l15;
#pragma unroll
            for (int j = 0; j < 4; ++j) {
                const int r = g * 4 + j;
                float p = acc[c][t][j] * inv[j];
                ab[(long)r * 2048 + col] = p;
                *(unsigned short*)(smem + r * 4096 + ((col * 2) ^ ((r & 7) << 4))) = f2b(p);
            }
        }
    __syncthreads();

    // ---- PV: out[16][16] per wave (wave = d-tile), V^T direct from L2 ----
    f32x4 o0 = (f32x4)(0.0f), o1 = (f32x4)(0.0f);
    f32x4 o2 = (f32x4)(0.0f), o3 = (f32x4)(0.0f);
    const char* vtile = vz + (long)(w * 16 + l15) * 4096;
    const char* prow = smem + l15 * 4096;
    const int psw = (l15 & 7) << 4;
#pragma unroll 4
    for (int ks = 0; ks < 64; ks += 4) {
        bf16v pa0 = *(const bf16v*)(prow + (((ks + 0) * 64 + g * 16) ^ psw));
        bf16v pa1 = *(const bf16v*)(prow + (((ks + 1) * 64 + g * 16) ^ psw));
        bf16v pa2 = *(const bf16v*)(prow + (((ks + 2) * 64 + g * 16) ^ psw));
        bf16v pa3 = *(const bf16v*)(prow + (((ks + 3) * 64 + g * 16) ^ psw));
        bf16v bv0 = *(const bf16v*)(vtile + (ks + 0) * 64 + g * 16);
        bf16v bv1 = *(const bf16v*)(vtile + (ks + 1) * 64 + g * 16);
        bf16v bv2 = *(const bf16v*)(vtile + (ks + 2) * 64 + g * 16);
        bf16v bv3 = *(const bf16v*)(vtile + (ks + 3) * 64 + g * 16);
        o0 = __builtin_amdgcn_mfma_f32_16x16x32_bf16(pa0, bv0, o0, 0, 0, 0);
        o1 = __builtin_amdgcn_mfma_f32_16x16x32_bf16(pa1, bv1, o1, 0, 0, 0);
        o2 = __builtin_amdgcn_mfma_f32_16x16x32_bf16(pa2, bv2, o2, 0, 0, 0);
        o3 = __builtin_amdgcn_mfma_f32_16x16x32_bf16(pa3, bv3, o3, 0, 0, 0);
    }
    o0 = o0 + o1 + o2 + o3;

    const int b = z >> 4, h = z & 15;
    const long tokbase = (long)b * 2048 + m0 + g * 4;
#pragma unroll
    for (int j = 0; j < 4; ++j)
        ao[(tokbase + j) * 1024 + h * 64 + w * 16 + l15] = f2b(o0[j]);
}

// ---------------- generic MFMA GEMM ----------------

enum { M_QKV = 0, M_VT = 1, M_RES = 2, M_RELU = 3 };

struct GArgs {
    const unsigned short* A;
    long lda;
    const unsigned short* B;
    long ldb;
    const float* bias;
    const float* resid;
    float* outF;
    unsigned short* outB;
    long ldo;
    int K;
};

template <int BM, int BN, int WR, int WC, int MODE>
__global__ __launch_bounds__(256) void gemm_k(GArgs g) {
    constexpr int MI = BM / (WR * 16), NI = BN / (WC * 16);
    __shared__ __align__(16) char sm[(BM + BN) * 128];
    char* sA = sm;
    char* sB = sm + BM * 128;
    const int tid = threadIdx.x, lane = tid & 63, wave = tid >> 6;
    const int wr = wave / WC, wc = wave % WC;
    const long m0 = (long)blockIdx.x * BM, n0 = (long)blockIdx.y * BN;

    const char* Ab = (const char*)(g.A + m0 * g.lda);
    const char* Bb = (const char*)(g.B + n0 * g.ldb);
    const long lda = g.lda, ldb = g.ldb;

    f32x4 acc[MI][NI];
#pragma unroll
    for (int mi = 0; mi < MI; mi++)
#pragma unroll
        for (int ni = 0; ni < NI; ni++) acc[mi][ni] = (f32x4)(0.0f);

    for (int k0 = 0; k0 < g.K; k0 += 64) {
#pragma unroll
        for (int i = 0; i < BM / 32; i++) {
            int c = i * 4 + wave;
            int p = c * 1024 + lane * 16;
            int row = p >> 7;
            int scb = (p & 127) ^ ((row & 7) << 4);
            gl_lds16(Ab + (long)row * (lda * 2) + (long)k0 * 2 + scb, sA + c * 1024);
        }
#pragma unroll
        for (int i = 0; i < BN / 32; i++) {
            int c = i * 4 + wave;
            int p = c * 1024 + lane * 16;
            int row = p >> 7;
            int scb = (p & 127) ^ ((row & 7) << 4);
            gl_lds16(Bb + (long)row * (ldb * 2) + (long)k0 * 2 + scb, sB + c * 1024);
        }
        __syncthreads();
#pragma unroll
        for (int ks = 0; ks < 2; ++ks) {
            const int cb = ks * 64 + (lane >> 4) * 16;
            bf16v af[MI], bfv[NI];
#pragma unroll
            for (int mi = 0; mi < MI; mi++) {
                int r = wr * (BM / WR) + mi * 16 + (lane & 15);
                af[mi] = *(const bf16v*)(sA + r * 128 + (cb ^ ((r & 7) << 4)));
            }
#pragma unroll
            for (int ni = 0; ni < NI; ni++) {
                int r = wc * (BN / WC) + ni * 16 + (lane & 15);
                bfv[ni] = *(const bf16v*)(sB + r * 128 + (cb ^ ((r & 7) << 4)));
            }
#pragma unroll
            for (int mi = 0; mi < MI; mi++)
#pragma unroll
                for (int ni = 0; ni < NI; ni++)
                    acc[mi][ni] = __builtin_amdgcn_mfma_f32_16x16x32_bf16(
                        af[mi], bfv[ni], acc[mi][ni], 0, 0, 0);
        }
        __syncthreads();
    }

    // epilogue: C/D layout col=lane&15, row=(lane>>4)*4+j
#pragma unroll
    for (int mi = 0; mi < MI; mi++)
#pragma unroll
        for (int ni = 0; ni < NI; ni++) {
            if constexpr (MODE == M_VT) {
                long r = m0 + wr * (BM / WR) + mi * 16 + (lane >> 4) * 4;
                long c = n0 + wc * (BN / WC) + ni * 16 + (lane & 15);
                float bi = g.bias[c];
                u16x4 u;
#pragma unroll
                for (int j = 0; j < 4; ++j) u[j] = f2b(acc[mi][ni][j] + bi);
                long b = r >> 11, s = r & 2047, h = c >> 6, d = c & 63;
                *(u16x4*)(g.outB + (b * 16 + h) * 131072 + d * 2048 + s) = u;
            } else {
#pragma unroll
                for (int j = 0; j < 4; ++j) {
                    long r = m0 + wr * (BM / WR) + mi * 16 + (lane >> 4) * 4 + j;
                    long c = n0 + wc * (BN / WC) + ni * 16 + (lane & 15);
                    float v = acc[mi][ni][j];
                    if constexpr (MODE == M_QKV) {
                        v += g.bias[c];
                        long b = r >> 11, s = r & 2047, h = c >> 6, d = c & 63;
                        g.outB[((b * 16 + h) * 2048 + s) * 64 + d] = f2b(v);
                    } else if constexpr (MODE == M_RES) {
                        long i = r * g.ldo + c;
                        g.outF[i] = v + g.bias[c] + g.resid[i];
                    } else {  // M_RELU
                        float t = v + g.bias[c];
                        g.outB[r * g.ldo + c] = f2b(t > 0.0f ? t : 0.0f);
                    }
                }
            }
        }
}

// ---------------- host ----------------

extern "C" void kernel_launch(void* const* d_in, const int* in_sizes, int n_in,
                              void* d_out, int out_size, void* d_ws, size_t ws_size,
                              hipStream_t stream) {
    const float* x = (const float*)d_in[0];
    const float* wq = (const float*)d_in[1];
    const float* bq = (const float*)d_in[2];
    const float* wk = (const float*)d_in[3];
    const float* bk = (const float*)d_in[4];
    const float* wv = (const float*)d_in[5];
    const float* bv = (const float*)d_in[6];
    const float* wo = (const float*)d_in[7];
    const float* bo = (const float*)d_in[8];
    const float* g1 = (const float*)d_in[9];
    const float* b1 = (const float*)d_in[10];
    const float* w1 = (const float*)d_in[11];
    const float* bf1 = (const float*)d_in[12];
    const float* w2 = (const float*)d_in[13];
    const float* bf2 = (const float*)d_in[14];
    const float* g2 = (const float*)d_in[15];
    const float* b2 = (const float*)d_in[16];

    float* out2 = (float*)d_out;
    float* attn = (float*)d_out + 8388608;

    char* ws = (char*)d_ws;
    size_t off = 0;
    auto alc = [&](size_t bytes) { size_t r = off; off += (bytes + 255) & ~(size_t)255; return r; };

    unsigned short* xb  = (unsigned short*)(ws + alc(16777216));
    unsigned short* wqT = (unsigned short*)(ws + alc(2097152));
    unsigned short* wkT = (unsigned short*)(ws + alc(2097152));
    unsigned short* wvT = (unsigned short*)(ws + alc(2097152));
    unsigned short* woT = (unsigned short*)(ws + alc(2097152));
    unsigned short* w1T = (unsigned short*)(ws + alc(8388608));
    unsigned short* w2T = (unsigned short*)(ws + alc(8388608));
    size_t qkvOff = alc(67108864);           // q,k,vt block; later reused by ff1
    unsigned short* qb = (unsigned short*)(ws + qkvOff);
    unsigned short* kb = qb + 8388608;
    unsigned short* vt = kb + 8388608;
    unsigned short* ff1 = qb;                // alias (q/k/vt dead by FFN1)
    size_t aoOff = alc(16777216);            // attn_out bf16; later out1 bf16
    unsigned short* ao  = (unsigned short*)(ws + aoOff);
    unsigned short* o1b = ao;                // alias
    size_t rOff = alc(33554432);             // resid1; later resid2
    float* r1 = (float*)(ws + rOff);
    float* r2 = r1;                          // alias
    float* o1f = (float*)(ws + alc(33554432));

    // 1. x -> bf16
    cvt_f32_bf16<<<8192, 256, 0, stream>>>(x, xb, 8388608);
    // 2. weight transposes -> [N][K] bf16
    transp_f32_bf16<<<dim3(32, 32), 256, 0, stream>>>(wq, wqT, 1024, 1024);
    transp_f32_bf16<<<dim3(32, 32), 256, 0, stream>>>(wk, wkT, 1024, 1024);
    transp_f32_bf16<<<dim3(32, 32), 256, 0, stream>>>(wv, wvT, 1024, 1024);
    transp_f32_bf16<<<dim3(32, 32), 256, 0, stream>>>(wo, woT, 1024, 1024);
    transp_f32_bf16<<<dim3(128, 32), 256, 0, stream>>>(w1, w1T, 1024, 4096);
    transp_f32_bf16<<<dim3(32, 128), 256, 0, stream>>>(w2, w2T, 4096, 1024);

    // 3. Q,K -> [b,h,s,d]; V -> V^T [b,h,d,s]
    {
        GArgs a{};
        a.A = xb; a.lda = 1024; a.ldb = 1024; a.K = 1024;
        a.B = wqT; a.bias = bq; a.outB = qb;
        gemm_k<128, 128, 2, 2, M_QKV><<<dim3(64, 8), 256, 0, stream>>>(a);
        a.B = wkT; a.bias = bk; a.outB = kb;
        gemm_k<128, 128, 2, 2, M_QKV><<<dim3(64, 8), 256, 0, stream>>>(a);
        a.B = wvT; a.bias = bv; a.outB = vt;
        gemm_k<128, 128, 2, 2, M_VT><<<dim3(64, 8), 256, 0, stream>>>(a);
    }
    // 4. fused scores+softmax+PV: writes attn (d_out) + ao
    attn_fused<<<8192, 256, 0, stream>>>(qb, kb, vt, attn, ao);
    // 5. out-proj + bias + residual(x) -> r1 fp32
    {
        GArgs a{};
        a.A = ao; a.lda = 1024; a.B = woT; a.ldb = 1024;
        a.bias = bo; a.resid = x; a.outF = r1; a.ldo = 1024; a.K = 1024;
        gemm_k<128, 128, 2, 2, M_RES><<<dim3(64, 8), 256, 0, stream>>>(a);
    }
    // 6. LN1 -> o1f fp32 + o1b bf16
    ln_rows<<<8192, 256, 0, stream>>>(r1, g1, b1, o1f, o1b);
    // 7. FFN1 + ReLU -> ff1 bf16
    {
        GArgs a{};
        a.A = o1b; a.lda = 1024; a.B = w1T; a.ldb = 1024;
        a.bias = bf1; a.outB = ff1; a.ldo = 4096; a.K = 1024;
        gemm_k<128, 128, 2, 2, M_RELU><<<dim3(64, 32), 256, 0, stream>>>(a);
    }
    // 8. FFN2 + bias + residual(out1) -> r2 fp32
    {
        GArgs a{};
        a.A = ff1; a.lda = 4096; a.B = w2T; a.ldb = 4096;
        a.bias = bf2; a.resid = o1f; a.outF = r2; a.ldo = 1024; a.K = 4096;
        gemm_k<128, 128, 2, 2, M_RES><<<dim3(64, 8), 256, 0, stream>>>(a);
    }
    // 9. LN2 -> out2 (d_out)
    ln_rows<<<8192, 256, 0, stream>>>(r2, g2, b2, out2, nullptr);

    (void)in_sizes; (void)n_in; (void)out_size; (void)ws_size;
}